// Round 5
// baseline (197.642 us; speedup 1.0000x reference)
//
#include <hip/hip_runtime.h>

// out[b,h,i,j] = x[b,h,i,j] - max(p[h],eps) * log1p(max(a[h],eps) * max(i-j,0))
// B=2, H=16, S=2048. Block-uniform h: grid = 32 slabs (b*16+h) x 128 chunks.
// 4096 blocks x 256 threads x 32 float4/thread = 2^25 float4 = exact cover.
// Batch-4 two-deep pipeline: ~32 data VGPRs -> <=64 total -> 8 waves/SIMD.

#define EPS 0.01f
#define LN2 0.69314718055994530942f

typedef float f32x4 __attribute__((ext_vector_type(4)));

__device__ __forceinline__ void load4(const f32x4* __restrict__ x, int idx0, int it,
                                      f32x4 (&buf)[4]) {
    #pragma unroll
    for (int k = 0; k < 4; ++k)
        buf[k] = __builtin_nontemporal_load(&x[idx0 + (it * 4 + k) * 256]);
}

__device__ __forceinline__ void proc4(f32x4* __restrict__ out, int idx0, int it,
                                      const f32x4 (&buf)[4], float a, float c) {
    #pragma unroll
    for (int k = 0; k < 4; ++k) {
        const int id = idx0 + (it * 4 + k) * 256;
        const int e  = id << 2;              // element index (< 2^27)
        const int j  = e & 2047;             // column
        const int i  = (e >> 11) & 2047;     // row
        const int d0 = i - j;
        f32x4 r;
        #pragma unroll
        for (int q = 0; q < 4; ++q) {
            int d = d0 - q;
            d = d > 0 ? d : 0;               // tril clamp; log1p(0)=0 above diag
            r[q] = fmaf(c, __log2f(fmaf(a, (float)d, 1.0f)), buf[k][q]);
        }
        __builtin_nontemporal_store(r, &out[id]);
    }
}

__global__ __launch_bounds__(256) void ParallelKerpleLog_50216757625001_kernel(
    const f32x4* __restrict__ x,
    const float* __restrict__ bias_p,
    const float* __restrict__ bias_a,
    f32x4* __restrict__ out)
{
    const int bid  = blockIdx.x;             // 4096 blocks
    const int slab = bid >> 7;               // b*16+h
    const int h    = slab & 15;              // block-uniform head -> SGPR constants
    const float a = fmaxf(bias_a[h], EPS);
    const float c = -fmaxf(bias_p[h], EPS) * LN2;   // bias = c * log2(1 + a*d)

    // base in float4 units: slab * 2^20 + chunk * 2^13
    const int base4 = (slab << 20) + ((bid & 127) << 13);
    const int idx0  = base4 + threadIdx.x;

    f32x4 vA[4], vB[4];                      // static double buffer (register-resident)

    load4(x, idx0, 0, vA);
    #pragma unroll 1
    for (int g = 0; g < 4; ++g) {            // 2 batches of 4 per iteration
        const int itA = 2 * g, itB = 2 * g + 1;
        load4(x, idx0, itB, vB);             // prefetch B while A computes
        proc4(out, idx0, itA, vA, a, c);
        if (g < 3) load4(x, idx0, itA + 2, vA);  // prefetch next A while B computes
        proc4(out, idx0, itB, vB, a, c);
    }
}

extern "C" void kernel_launch(void* const* d_in, const int* in_sizes, int n_in,
                              void* d_out, int out_size, void* d_ws, size_t ws_size,
                              hipStream_t stream) {
    const f32x4* x       = (const f32x4*)d_in[0];
    const float*  bias_p = (const float*)d_in[1];
    const float*  bias_a = (const float*)d_in[2];
    f32x4* out = (f32x4*)d_out;

    // 32 slabs x 128 chunks = 4096 blocks; exact cover of 2^25 float4s.
    ParallelKerpleLog_50216757625001_kernel<<<4096, 256, 0, stream>>>(
        x, bias_p, bias_a, out);
}